// Round 4
// baseline (646.433 us; speedup 1.0000x reference)
//
#include <hip/hip_runtime.h>

#define F   128
#define FQ  32   // F/4 (float4 per row)
#define FU  64   // uints per bf16 row (128 bf16 = 64 uints)
#define CPAD 5   // row-counter padding shift: 32 ints = 128 B = 1 L2 line/row

// pack two fp32 -> two bf16 (RNE) in one uint (a = low = even feature)
__device__ __forceinline__ unsigned int f2bf2(float a, float b) {
    unsigned int ua = __float_as_uint(a);
    unsigned int ub = __float_as_uint(b);
    ua = (ua + 0x7fffu + ((ua >> 16) & 1u)) >> 16;
    ub = (ub + 0x7fffu + ((ub >> 16) & 1u)) >> 16;
    return ua | (ub << 16);
}

// ---------------------------------------------------------------------------
// Dense GEMM: H[n][f] = sum_k In[n][k] * W[k][f], output packed bf16.
// If BN: input transformed as relu(a[k]*In[n][k] + c[k]) during LDS staging.
// Tile: 32 nodes x 128 features per block of 256 threads.
// ---------------------------------------------------------------------------
template <bool BN>
__global__ __launch_bounds__(256) void gemm_kernel(const float* __restrict__ X,
                                                   const float* __restrict__ W,
                                                   const float* __restrict__ ac,
                                                   unsigned int* __restrict__ Hb,
                                                   int nNodes) {
    __shared__ float4 wlds[F * FQ];   // wlds[k*32 + fq] = W[k][4fq .. 4fq+3]
    __shared__ float4 xt4[F * 8];     // xt[k*32 + n] = Xtile[n][k] (transposed)
    float* xt = (float*)xt4;

    const int tid = threadIdx.x;
    const int bn0 = blockIdx.x * 32;

    const float4* W4 = (const float4*)W;
    #pragma unroll
    for (int i = tid; i < F * FQ; i += 256) wlds[i] = W4[i];

    const float4* X4 = (const float4*)X;
    const float4* A4 = (const float4*)ac;        // a[f] scale
    const float4* C4 = (const float4*)(ac + F);  // c[f] shift
    for (int i = tid; i < 32 * FQ; i += 256) {
        int n = i >> 5;       // node within tile 0..31
        int kq = i & 31;      // feature quad 0..31
        int node = bn0 + n;
        float4 v = make_float4(0.f, 0.f, 0.f, 0.f);
        if (node < nNodes) v = X4[(size_t)node * FQ + kq];
        if (BN) {
            float4 a = A4[kq], c = C4[kq];
            v.x = fmaxf(fmaf(a.x, v.x, c.x), 0.f);
            v.y = fmaxf(fmaf(a.y, v.y, c.y), 0.f);
            v.z = fmaxf(fmaf(a.z, v.z, c.z), 0.f);
            v.w = fmaxf(fmaf(a.w, v.w, c.w), 0.f);
        }
        xt[(4 * kq + 0) * 32 + n] = v.x;
        xt[(4 * kq + 1) * 32 + n] = v.y;
        xt[(4 * kq + 2) * 32 + n] = v.z;
        xt[(4 * kq + 3) * 32 + n] = v.w;
    }
    __syncthreads();

    const int fq = tid & 31;   // feature quad  -> features 4fq..4fq+3
    const int ng = tid >> 5;   // node group 0..7 -> nodes 4ng..4ng+3

    float acc[4][4];
    #pragma unroll
    for (int i = 0; i < 4; ++i)
        #pragma unroll
        for (int j = 0; j < 4; ++j) acc[i][j] = 0.f;

    #pragma unroll 8
    for (int k = 0; k < F; ++k) {
        float4 wv = wlds[k * 32 + fq];
        float4 xv = xt4[k * 8 + ng];
        float xa[4] = {xv.x, xv.y, xv.z, xv.w};
        float wa[4] = {wv.x, wv.y, wv.z, wv.w};
        #pragma unroll
        for (int i = 0; i < 4; ++i)
            #pragma unroll
            for (int j = 0; j < 4; ++j)
                acc[i][j] = fmaf(xa[i], wa[j], acc[i][j]);
    }

    uint2* H2 = (uint2*)Hb;   // row = 32 uint2
    #pragma unroll
    for (int i = 0; i < 4; ++i) {
        int node = bn0 + 4 * ng + i;
        if (node < nNodes)
            H2[(size_t)node * 32 + fq] =
                make_uint2(f2bf2(acc[i][0], acc[i][1]), f2bf2(acc[i][2], acc[i][3]));
    }
}

// ---------------------------------------------------------------------------
// CSR build: count -> 3-phase parallel scan -> scatter
// Row counters padded to 1 per 128-B line (index row<<CPAD) to kill the
// false-sharing measured in round 3 (256 atomics/line -> 16 per-address).
// ---------------------------------------------------------------------------
__global__ __launch_bounds__(256) void count_kernel(const int* __restrict__ row,
                                                    int* __restrict__ cntP, int E) {
    int t = blockIdx.x * 256 + threadIdx.x;
    int e0 = t * 4;
    if (e0 + 3 < E) {
        int4 r = ((const int4*)row)[t];
        atomicAdd(&cntP[(size_t)r.x << CPAD], 1);
        atomicAdd(&cntP[(size_t)r.y << CPAD], 1);
        atomicAdd(&cntP[(size_t)r.z << CPAD], 1);
        atomicAdd(&cntP[(size_t)r.w << CPAD], 1);
    } else {
        for (int j = 0; j < 4; ++j)
            if (e0 + j < E) atomicAdd(&cntP[(size_t)row[e0 + j] << CPAD], 1);
    }
}

// phase A: per-block (1024 rows) sums of padded counters
__global__ __launch_bounds__(256) void scanA_kernel(const int* __restrict__ cntP,
                                                    int* __restrict__ blockSum, int N) {
    int t = threadIdx.x;
    int i0 = blockIdx.x * 1024 + t * 4;
    int s = 0;
    #pragma unroll
    for (int j = 0; j < 4; ++j)
        if (i0 + j < N) s += cntP[(size_t)(i0 + j) << CPAD];
    #pragma unroll
    for (int off = 32; off > 0; off >>= 1) s += __shfl_down(s, off, 64);
    __shared__ int ws[4];
    if ((t & 63) == 0) ws[t >> 6] = s;
    __syncthreads();
    if (t == 0) blockSum[blockIdx.x] = ws[0] + ws[1] + ws[2] + ws[3];
}

// phase B: single block scans <=1024 block sums -> exclusive block offsets
__global__ __launch_bounds__(1024) void scanB_kernel(const int* __restrict__ blockSum,
                                                     int* __restrict__ blockOff,
                                                     int nb, int* __restrict__ rowptr,
                                                     int N, int E) {
    __shared__ int sh[1024];
    int t = threadIdx.x;
    int v = (t < nb) ? blockSum[t] : 0;
    sh[t] = v;
    __syncthreads();
    #pragma unroll
    for (int off = 1; off < 1024; off <<= 1) {
        int add = (t >= off) ? sh[t - off] : 0;
        __syncthreads();
        sh[t] += add;
        __syncthreads();
    }
    if (t < nb) blockOff[t] = sh[t] - v;
    if (t == 0) rowptr[N] = E;
}

// phase C: rescan counters, add block offset -> rowptr (compact) and
// write-back the exclusive start into the padded slot (reused as wptr).
__global__ __launch_bounds__(256) void scanC_kernel(int* __restrict__ cntP,
                                                    const int* __restrict__ blockOff,
                                                    int* __restrict__ rowptr, int N) {
    int t = threadIdx.x;
    int i0 = blockIdx.x * 1024 + t * 4;
    int v0 = 0, v1 = 0, v2 = 0, v3 = 0;
    if (i0 + 0 < N) v0 = cntP[(size_t)(i0 + 0) << CPAD];
    if (i0 + 1 < N) v1 = cntP[(size_t)(i0 + 1) << CPAD];
    if (i0 + 2 < N) v2 = cntP[(size_t)(i0 + 2) << CPAD];
    if (i0 + 3 < N) v3 = cntP[(size_t)(i0 + 3) << CPAD];
    int s = v0 + v1 + v2 + v3;
    int lane = t & 63, wv = t >> 6;
    int inc = s;
    #pragma unroll
    for (int off = 1; off < 64; off <<= 1) {
        int up = __shfl_up(inc, off, 64);
        if (lane >= off) inc += up;
    }
    __shared__ int wsum[4];
    if (lane == 63) wsum[wv] = inc;
    __syncthreads();
    int woff = 0;
    #pragma unroll
    for (int j = 0; j < 4; ++j) woff += (j < wv) ? wsum[j] : 0;
    int excl = blockOff[blockIdx.x] + woff + inc - s;
    if (i0 + 0 < N) { rowptr[i0 + 0] = excl;                cntP[(size_t)(i0 + 0) << CPAD] = excl; }
    if (i0 + 1 < N) { rowptr[i0 + 1] = excl + v0;           cntP[(size_t)(i0 + 1) << CPAD] = excl + v0; }
    if (i0 + 2 < N) { rowptr[i0 + 2] = excl + v0 + v1;      cntP[(size_t)(i0 + 2) << CPAD] = excl + v0 + v1; }
    if (i0 + 3 < N) { rowptr[i0 + 3] = excl + v0 + v1 + v2; cntP[(size_t)(i0 + 3) << CPAD] = excl + v0 + v1 + v2; }
}

// scatter: 4 edges/thread, padded-counter bump, nontemporal 8-B pair store
// (bypass L2 so the cross-XCD partial-line writes don't thrash dirty lines).
__global__ __launch_bounds__(256) void scatter_kernel(const int* __restrict__ row,
                                                      const int* __restrict__ col,
                                                      const float* __restrict__ w,
                                                      int* __restrict__ wptrP,
                                                      long long* __restrict__ pairs, int E) {
    int t = blockIdx.x * 256 + threadIdx.x;
    int e0 = t * 4;
    if (e0 + 3 < E) {
        int4 r = ((const int4*)row)[t];
        int4 c = ((const int4*)col)[t];
        float4 wt = ((const float4*)w)[t];
        int ra[4] = {r.x, r.y, r.z, r.w};
        int ca[4] = {c.x, c.y, c.z, c.w};
        float wa[4] = {wt.x, wt.y, wt.z, wt.w};
        #pragma unroll
        for (int j = 0; j < 4; ++j) {
            int pos = atomicAdd(&wptrP[(size_t)ra[j] << CPAD], 1);
            long long v = ((long long)__float_as_int(wa[j]) << 32) | (unsigned int)ca[j];
            __builtin_nontemporal_store(v, &pairs[pos]);
        }
    } else {
        for (int j = 0; j < 4; ++j) {
            int e = e0 + j;
            if (e >= E) break;
            int pos = atomicAdd(&wptrP[(size_t)row[e] << CPAD], 1);
            long long v = ((long long)__float_as_int(w[e]) << 32) | (unsigned int)col[e];
            __builtin_nontemporal_store(v, &pairs[pos]);
        }
    }
}

// ---------------------------------------------------------------------------
// CSR SpMM, bf16 gather operand: one wave per row, lane l covers feats 2l,2l+1.
// 8-edge preload: 8 pair-loads + 8 gathers in flight before the FMA block.
// ---------------------------------------------------------------------------
__global__ __launch_bounds__(256) void spmm_csr_kernel(const int* __restrict__ rowptr,
                                                       const int2* __restrict__ pairs,
                                                       const unsigned int* __restrict__ Hb,
                                                       const float* __restrict__ bias,
                                                       float* __restrict__ out, int N) {
    int r = blockIdx.x * 4 + (threadIdx.x >> 6);
    if (r >= N) return;
    int l = threadIdx.x & 63;
    float2 acc = bias ? ((const float2*)bias)[l] : make_float2(0.f, 0.f);
    int i = rowptr[r], end = rowptr[r + 1];

    for (; i + 8 <= end; i += 8) {
        int2 p[8];
        #pragma unroll
        for (int j = 0; j < 8; ++j) p[j] = pairs[i + j];
        unsigned int g[8];
        #pragma unroll
        for (int j = 0; j < 8; ++j) g[j] = Hb[(size_t)p[j].x * FU + l];
        #pragma unroll
        for (int j = 0; j < 8; ++j) {
            float wt = __int_as_float(p[j].y);
            acc.x = fmaf(wt, __uint_as_float(g[j] << 16), acc.x);
            acc.y = fmaf(wt, __uint_as_float(g[j] & 0xffff0000u), acc.y);
        }
    }
    if (i + 4 <= end) {
        int2 p[4];
        #pragma unroll
        for (int j = 0; j < 4; ++j) p[j] = pairs[i + j];
        unsigned int g[4];
        #pragma unroll
        for (int j = 0; j < 4; ++j) g[j] = Hb[(size_t)p[j].x * FU + l];
        #pragma unroll
        for (int j = 0; j < 4; ++j) {
            float wt = __int_as_float(p[j].y);
            acc.x = fmaf(wt, __uint_as_float(g[j] << 16), acc.x);
            acc.y = fmaf(wt, __uint_as_float(g[j] & 0xffff0000u), acc.y);
        }
        i += 4;
    }
    for (; i < end; ++i) {
        int2 p = pairs[i];
        unsigned int g = Hb[(size_t)p.x * FU + l];
        float wt = __int_as_float(p.y);
        acc.x = fmaf(wt, __uint_as_float(g << 16), acc.x);
        acc.y = fmaf(wt, __uint_as_float(g & 0xffff0000u), acc.y);
    }
    ((float2*)out)[(size_t)r * 64 + l] = acc;
}

// ---------------------------------------------------------------------------
// BN batch statistics: per-feature sum and sumsq over nodes (fp32 input).
// ---------------------------------------------------------------------------
__global__ __launch_bounds__(256) void bnstats_kernel(const float* __restrict__ H,
                                                      float* __restrict__ sums,
                                                      int nNodes) {
    int f = threadIdx.x & 127;
    int g = threadIdx.x >> 7;  // 0..1
    int stride = gridDim.x * 2;
    float s = 0.f, sq = 0.f;
    for (int n = blockIdx.x * 2 + g; n < nNodes; n += stride) {
        float v = H[(size_t)n * F + f];
        s += v;
        sq = fmaf(v, v, sq);
    }
    __shared__ float red[256];
    red[threadIdx.x] = s;
    __syncthreads();
    float sfull = 0.f;
    if (g == 0) sfull = red[f] + red[f + 128];
    __syncthreads();
    red[threadIdx.x] = sq;
    __syncthreads();
    if (g == 0) {
        float sqfull = red[f] + red[f + 128];
        atomicAdd(&sums[f], sfull);
        atomicAdd(&sums[128 + f], sqfull);
    }
}

// Fold mean/var/gamma/beta into per-feature scale a and shift c.
// Note: layer-1 bias b1 cancels exactly in BN (mean subtraction) -> unused.
__global__ void bnfinal_kernel(const float* __restrict__ sums,
                               const float* __restrict__ gamma,
                               const float* __restrict__ beta,
                               float* __restrict__ ac, float invN) {
    int f = threadIdx.x;
    float mean = sums[f] * invN;
    float var = sums[128 + f] * invN - mean * mean;
    float a = gamma[f] * rsqrtf(var + 1e-5f);
    ac[f] = a;
    ac[128 + f] = beta[f] - mean * a;
}

extern "C" void kernel_launch(void* const* d_in, const int* in_sizes, int n_in,
                              void* d_out, int out_size, void* d_ws, size_t ws_size,
                              hipStream_t stream) {
    const float* x    = (const float*)d_in[0];
    const int*   erow = (const int*)d_in[1];
    const int*   ecol = (const int*)d_in[2];
    const float* ew   = (const float*)d_in[3];
    const float* W1   = (const float*)d_in[4];
    // d_in[5] = b1: unused — cancels exactly under BatchNorm mean subtraction.
    const float* W2   = (const float*)d_in[6];
    const float* b2   = (const float*)d_in[7];
    const float* gmm  = (const float*)d_in[8];
    const float* beta = (const float*)d_in[9];
    float* out = (float*)d_out;

    const int N = in_sizes[0] / F;   // 100000
    const int E = in_sizes[1];       // 1600000

    // ---- workspace carve-up (all offsets keep 16-B alignment) ----
    float*        buf1   = (float*)d_ws;                    // N*F fp32: spmm1 out
    unsigned int* Hb     = (unsigned int*)(buf1 + (size_t)N * F); // N*FU: bf16 H
    float*        stats  = (float*)(Hb + (size_t)N * FU);   // 256
    float*        ac     = stats + 256;                     // 256
    int*          cntP   = (int*)(ac + 256);                // N<<CPAD (padded counters)
    int*          rowptr = cntP + ((size_t)N << CPAD);      // N+2
    int*          blockSum = rowptr + N + 2;                // 1024
    int*          blockOff = blockSum + 1024;               // 1024 (+pad to 16B)
    long long*    pairs  = (long long*)(blockOff + 1024 + 2); // E

    const int gemmGrid = (N + 31) / 32;
    const int e4Grid   = ((E + 3) / 4 + 255) / 256;
    const int nb       = (N + 1023) / 1024;  // scan blocks
    const int spmmGrid = (N + 3) / 4;

    hipMemsetAsync(stats, 0, 256 * sizeof(float), stream);
    hipMemsetAsync(cntP, 0, ((size_t)N << CPAD) * sizeof(int), stream);

    // ---- build CSR (shared by both SpMM layers) ----
    count_kernel<<<e4Grid, 256, 0, stream>>>(erow, cntP, E);
    scanA_kernel<<<nb, 256, 0, stream>>>(cntP, blockSum, N);
    scanB_kernel<<<1, 1024, 0, stream>>>(blockSum, blockOff, nb, rowptr, N, E);
    scanC_kernel<<<nb, 256, 0, stream>>>(cntP, blockOff, rowptr, N);
    scatter_kernel<<<e4Grid, 256, 0, stream>>>(erow, ecol, ew, cntP, pairs, E);

    // Layer 1: Hb = bf16(x @ W1) ; buf1 = A @ Hb
    gemm_kernel<false><<<gemmGrid, 256, 0, stream>>>(x, W1, nullptr, Hb, N);
    spmm_csr_kernel<<<spmmGrid, 256, 0, stream>>>(rowptr, (const int2*)pairs, Hb,
                                                  nullptr, buf1, N);
    // BN stats + fold
    bnstats_kernel<<<400, 256, 0, stream>>>(buf1, stats, N);
    bnfinal_kernel<<<1, 128, 0, stream>>>(stats, gmm, beta, ac, 1.0f / (float)N);
    // Layer 2: Hb = bf16(relu(bn(buf1)) @ W2) ; out = A @ Hb + b2
    gemm_kernel<true><<<gemmGrid, 256, 0, stream>>>(buf1, W2, ac, Hb, N);
    spmm_csr_kernel<<<spmmGrid, 256, 0, stream>>>(rowptr, (const int2*)pairs, Hb,
                                                  b2, out, N);
}

// Round 5
// 519.616 us; speedup vs baseline: 1.2441x; 1.2441x over previous
//
#include <hip/hip_runtime.h>

#define F    128
#define FQ   32    // F/4 (float4 per row)
#define FU   64    // uints per bf16 row
#define RPB  128   // rows per bucket
#define BSH  7     // log2(RPB)
#define TILE 2048  // edges per histogram tile (256 thr x 8)
#define SCAP 4096  // max edges per bucket section (mean 2046, +45 sigma)

// pack two fp32 -> two bf16 (RNE) in one uint (a = low = even feature)
__device__ __forceinline__ unsigned int f2bf2(float a, float b) {
    unsigned int ua = __float_as_uint(a);
    unsigned int ub = __float_as_uint(b);
    ua = (ua + 0x7fffu + ((ua >> 16) & 1u)) >> 16;
    ub = (ub + 0x7fffu + ((ub >> 16) & 1u)) >> 16;
    return ua | (ub << 16);
}

// ---------------------------------------------------------------------------
// Dense GEMM: H[n][f] = sum_k In[n][k] * W[k][f], output packed bf16.
// If BN: input transformed as relu(a[k]*In[n][k] + c[k]) during LDS staging.
// ---------------------------------------------------------------------------
template <bool BN>
__global__ __launch_bounds__(256) void gemm_kernel(const float* __restrict__ X,
                                                   const float* __restrict__ W,
                                                   const float* __restrict__ ac,
                                                   unsigned int* __restrict__ Hb,
                                                   int nNodes) {
    __shared__ float4 wlds[F * FQ];   // wlds[k*32 + fq] = W[k][4fq .. 4fq+3]
    __shared__ float4 xt4[F * 8];     // xt[k*32 + n] = Xtile[n][k] (transposed)
    float* xt = (float*)xt4;

    const int tid = threadIdx.x;
    const int bn0 = blockIdx.x * 32;

    const float4* W4 = (const float4*)W;
    #pragma unroll
    for (int i = tid; i < F * FQ; i += 256) wlds[i] = W4[i];

    const float4* X4 = (const float4*)X;
    const float4* A4 = (const float4*)ac;        // a[f] scale
    const float4* C4 = (const float4*)(ac + F);  // c[f] shift
    for (int i = tid; i < 32 * FQ; i += 256) {
        int n = i >> 5;
        int kq = i & 31;
        int node = bn0 + n;
        float4 v = make_float4(0.f, 0.f, 0.f, 0.f);
        if (node < nNodes) v = X4[(size_t)node * FQ + kq];
        if (BN) {
            float4 a = A4[kq], c = C4[kq];
            v.x = fmaxf(fmaf(a.x, v.x, c.x), 0.f);
            v.y = fmaxf(fmaf(a.y, v.y, c.y), 0.f);
            v.z = fmaxf(fmaf(a.z, v.z, c.z), 0.f);
            v.w = fmaxf(fmaf(a.w, v.w, c.w), 0.f);
        }
        xt[(4 * kq + 0) * 32 + n] = v.x;
        xt[(4 * kq + 1) * 32 + n] = v.y;
        xt[(4 * kq + 2) * 32 + n] = v.z;
        xt[(4 * kq + 3) * 32 + n] = v.w;
    }
    __syncthreads();

    const int fq = tid & 31;
    const int ng = tid >> 5;

    float acc[4][4];
    #pragma unroll
    for (int i = 0; i < 4; ++i)
        #pragma unroll
        for (int j = 0; j < 4; ++j) acc[i][j] = 0.f;

    #pragma unroll 8
    for (int k = 0; k < F; ++k) {
        float4 wv = wlds[k * 32 + fq];
        float4 xv = xt4[k * 8 + ng];
        float xa[4] = {xv.x, xv.y, xv.z, xv.w};
        float wa[4] = {wv.x, wv.y, wv.z, wv.w};
        #pragma unroll
        for (int i = 0; i < 4; ++i)
            #pragma unroll
            for (int j = 0; j < 4; ++j)
                acc[i][j] = fmaf(xa[i], wa[j], acc[i][j]);
    }

    uint2* H2 = (uint2*)Hb;
    #pragma unroll
    for (int i = 0; i < 4; ++i) {
        int node = bn0 + 4 * ng + i;
        if (node < nNodes)
            H2[(size_t)node * 32 + fq] =
                make_uint2(f2bf2(acc[i][0], acc[i][1]), f2bf2(acc[i][2], acc[i][3]));
    }
}

// ---------------------------------------------------------------------------
// CSR build via deterministic bucket sort — NO returning global atomics.
// Bucket = row >> BSH (128 rows). NB <= 1024, nT <= 1024 assumed.
// ---------------------------------------------------------------------------

// S1: per-tile histogram over buckets (LDS atomics), coalesced global write.
__global__ __launch_bounds__(256) void histo_kernel(const int* __restrict__ row,
                                                    int* __restrict__ hist,
                                                    int NB, int E) {
    __shared__ int h[1024];
    int t = threadIdx.x;
    for (int i = t; i < NB; i += 256) h[i] = 0;
    __syncthreads();
    int base = blockIdx.x * TILE + t * 8;
    if (base + 7 < E) {
        int4 a = ((const int4*)row)[(base >> 2) + 0];
        int4 b = ((const int4*)row)[(base >> 2) + 1];
        atomicAdd(&h[a.x >> BSH], 1); atomicAdd(&h[a.y >> BSH], 1);
        atomicAdd(&h[a.z >> BSH], 1); atomicAdd(&h[a.w >> BSH], 1);
        atomicAdd(&h[b.x >> BSH], 1); atomicAdd(&h[b.y >> BSH], 1);
        atomicAdd(&h[b.z >> BSH], 1); atomicAdd(&h[b.w >> BSH], 1);
    } else {
        for (int j = 0; j < 8; ++j)
            if (base + j < E) atomicAdd(&h[row[base + j] >> BSH], 1);
    }
    __syncthreads();
    for (int i = t; i < NB; i += 256) hist[(size_t)blockIdx.x * NB + i] = h[i];
}

// S2a: bucket totals (one block per bucket, strided reads over tiles).
__global__ __launch_bounds__(256) void btot_kernel(const int* __restrict__ hist,
                                                   int* __restrict__ total,
                                                   int nT, int NB) {
    int b = blockIdx.x;
    int s = 0;
    for (int t = threadIdx.x; t < nT; t += 256) s += hist[(size_t)t * NB + b];
    __shared__ int red[256];
    red[threadIdx.x] = s;
    __syncthreads();
    for (int o = 128; o > 0; o >>= 1) {
        if (threadIdx.x < o) red[threadIdx.x] += red[threadIdx.x + o];
        __syncthreads();
    }
    if (threadIdx.x == 0) total[b] = red[0];
}

// S2b: single-block exclusive scan of bucket totals -> start[NB+1].
__global__ __launch_bounds__(1024) void bstart_kernel(const int* __restrict__ total,
                                                      int* __restrict__ start,
                                                      int NB, int E) {
    __shared__ int sh[1024];
    int t = threadIdx.x;
    int v = (t < NB) ? total[t] : 0;
    sh[t] = v;
    __syncthreads();
    #pragma unroll
    for (int o = 1; o < 1024; o <<= 1) {
        int add = (t >= o) ? sh[t - o] : 0;
        __syncthreads();
        sh[t] += add;
        __syncthreads();
    }
    if (t < NB) start[t] = sh[t] - v;
    if (t == 0) start[NB] = E;
}

// S2c: per-bucket exclusive scan over tiles -> off[b*nT+t] (coalesced write).
__global__ __launch_bounds__(1024) void boff_kernel(const int* __restrict__ hist,
                                                    const int* __restrict__ start,
                                                    int* __restrict__ off,
                                                    int nT, int NB) {
    __shared__ int sh[1024];
    int b = blockIdx.x, t = threadIdx.x;
    int v = (t < nT) ? hist[(size_t)t * NB + b] : 0;
    sh[t] = v;
    __syncthreads();
    #pragma unroll
    for (int o = 1; o < 1024; o <<= 1) {
        int add = (t >= o) ? sh[t - o] : 0;
        __syncthreads();
        sh[t] += add;
        __syncthreads();
    }
    if (t < nT) off[(size_t)b * nT + t] = start[b] + sh[t] - v;
}

// S3: place edges into bucket-partitioned tmp. Rank within tile via LDS atomic
// (cheap); position = off[bucket][tile] + rank. Packs (rowLocal<<25 | col, w).
__global__ __launch_bounds__(256) void bplace_kernel(const int* __restrict__ row,
                                                     const int* __restrict__ col,
                                                     const float* __restrict__ w,
                                                     const int* __restrict__ off,
                                                     int2* __restrict__ tmp,
                                                     int nT, int NB, int E) {
    __shared__ int h[1024];
    int t = threadIdx.x, tile = blockIdx.x;
    for (int i = t; i < NB; i += 256) h[i] = 0;
    __syncthreads();
    int base = tile * TILE + t * 8;
    int r[8], c[8];
    float ww[8];
    int nv = 0;
    if (base + 7 < E) {
        int4 ra = ((const int4*)row)[(base >> 2) + 0];
        int4 rb = ((const int4*)row)[(base >> 2) + 1];
        int4 ca = ((const int4*)col)[(base >> 2) + 0];
        int4 cb = ((const int4*)col)[(base >> 2) + 1];
        float4 wa = ((const float4*)w)[(base >> 2) + 0];
        float4 wb = ((const float4*)w)[(base >> 2) + 1];
        r[0] = ra.x; r[1] = ra.y; r[2] = ra.z; r[3] = ra.w;
        r[4] = rb.x; r[5] = rb.y; r[6] = rb.z; r[7] = rb.w;
        c[0] = ca.x; c[1] = ca.y; c[2] = ca.z; c[3] = ca.w;
        c[4] = cb.x; c[5] = cb.y; c[6] = cb.z; c[7] = cb.w;
        ww[0] = wa.x; ww[1] = wa.y; ww[2] = wa.z; ww[3] = wa.w;
        ww[4] = wb.x; ww[5] = wb.y; ww[6] = wb.z; ww[7] = wb.w;
        nv = 8;
    } else {
        for (int j = 0; j < 8; ++j)
            if (base + j < E) { r[nv] = row[base + j]; c[nv] = col[base + j];
                                ww[nv] = w[base + j]; ++nv; }
    }
    #pragma unroll 8
    for (int j = 0; j < 8; ++j) {
        if (j >= nv) break;
        int b = r[j] >> BSH;
        int rank = atomicAdd(&h[b], 1);
        int pos = off[(size_t)b * nT + tile] + rank;
        tmp[pos] = make_int2(((r[j] & (RPB - 1)) << 25) | c[j], __float_as_int(ww[j]));
    }
}

// S4: per-bucket counting sort. Section staged in registers, placed into LDS,
// written out coalesced. Also emits rowptr (subsumes count/scan kernels).
__global__ __launch_bounds__(256) void bsort_kernel(const int2* __restrict__ tmp,
                                                    const int* __restrict__ start,
                                                    int2* __restrict__ pairs,
                                                    int* __restrict__ rowptr,
                                                    int N, int NB, int E) {
    __shared__ int cntB[RPB];   // bump counters
    __shared__ int cntS[RPB];   // saved exclusive offsets
    __shared__ int sc[RPB];
    __shared__ int2 outP[SCAP];
    int b = blockIdx.x, t = threadIdx.x;
    int s0 = start[b], s1 = start[b + 1];
    int len = s1 - s0;
    if (len > SCAP) len = SCAP;   // safety clamp (never hit for this data)

    if (t < RPB) cntB[t] = 0;
    __syncthreads();

    int2 p[16];
    int np = 0;
    #pragma unroll
    for (int k = 0; k < 16; ++k) {
        int i = t + k * 256;
        if (i < len) { p[k] = tmp[s0 + i]; ++np; }
    }
    #pragma unroll
    for (int k = 0; k < 16; ++k) {
        if (k >= np) break;
        atomicAdd(&cntB[((unsigned)p[k].x) >> 25], 1);
    }
    __syncthreads();
    // exclusive scan of 128 counts (Hillis-Steele, block-wide syncs)
    int val = (t < RPB) ? cntB[t] : 0;
    if (t < RPB) sc[t] = val;
    __syncthreads();
    #pragma unroll
    for (int o = 1; o < RPB; o <<= 1) {
        int add = (t < RPB && t >= o) ? sc[t - o] : 0;
        __syncthreads();
        if (t < RPB) sc[t] += add;
        __syncthreads();
    }
    if (t < RPB) { int ex = sc[t] - val; cntB[t] = ex; cntS[t] = ex; }
    __syncthreads();
    // place into LDS
    #pragma unroll
    for (int k = 0; k < 16; ++k) {
        if (k >= np) break;
        int rl = ((unsigned)p[k].x) >> 25;
        int lr = atomicAdd(&cntB[rl], 1);
        outP[lr] = make_int2(p[k].x & 0x1ffffff, p[k].y);
    }
    __syncthreads();
    // coalesced write-out
    for (int i = t; i < len; i += 256) pairs[s0 + i] = outP[i];
    // rowptr
    int r0 = b * RPB;
    if (t < RPB && r0 + t < N) rowptr[r0 + t] = s0 + cntS[t];
    if (b == NB - 1 && t == 0) rowptr[N] = E;
}

// ---------------------------------------------------------------------------
// CSR SpMM, bf16 gather operand: one wave per row, lane l covers feats 2l,2l+1.
// 16-edge preload keeps 16 pair-loads + 16 gathers in flight.
// ---------------------------------------------------------------------------
__global__ __launch_bounds__(256) void spmm_csr_kernel(const int* __restrict__ rowptr,
                                                       const int2* __restrict__ pairs,
                                                       const unsigned int* __restrict__ Hb,
                                                       const float* __restrict__ bias,
                                                       float* __restrict__ out, int N) {
    int r = blockIdx.x * 4 + (threadIdx.x >> 6);
    if (r >= N) return;
    int l = threadIdx.x & 63;
    float2 acc = bias ? ((const float2*)bias)[l] : make_float2(0.f, 0.f);
    int i = rowptr[r], end = rowptr[r + 1];

    for (; i + 16 <= end; i += 16) {
        int2 p[16];
        #pragma unroll
        for (int j = 0; j < 16; ++j) p[j] = pairs[i + j];
        unsigned int g[16];
        #pragma unroll
        for (int j = 0; j < 16; ++j) g[j] = Hb[(size_t)p[j].x * FU + l];
        #pragma unroll
        for (int j = 0; j < 16; ++j) {
            float wt = __int_as_float(p[j].y);
            acc.x = fmaf(wt, __uint_as_float(g[j] << 16), acc.x);
            acc.y = fmaf(wt, __uint_as_float(g[j] & 0xffff0000u), acc.y);
        }
    }
    if (i + 8 <= end) {
        int2 p[8];
        #pragma unroll
        for (int j = 0; j < 8; ++j) p[j] = pairs[i + j];
        unsigned int g[8];
        #pragma unroll
        for (int j = 0; j < 8; ++j) g[j] = Hb[(size_t)p[j].x * FU + l];
        #pragma unroll
        for (int j = 0; j < 8; ++j) {
            float wt = __int_as_float(p[j].y);
            acc.x = fmaf(wt, __uint_as_float(g[j] << 16), acc.x);
            acc.y = fmaf(wt, __uint_as_float(g[j] & 0xffff0000u), acc.y);
        }
        i += 8;
    }
    if (i + 4 <= end) {
        int2 p[4];
        #pragma unroll
        for (int j = 0; j < 4; ++j) p[j] = pairs[i + j];
        unsigned int g[4];
        #pragma unroll
        for (int j = 0; j < 4; ++j) g[j] = Hb[(size_t)p[j].x * FU + l];
        #pragma unroll
        for (int j = 0; j < 4; ++j) {
            float wt = __int_as_float(p[j].y);
            acc.x = fmaf(wt, __uint_as_float(g[j] << 16), acc.x);
            acc.y = fmaf(wt, __uint_as_float(g[j] & 0xffff0000u), acc.y);
        }
        i += 4;
    }
    for (; i < end; ++i) {
        int2 p = pairs[i];
        unsigned int g = Hb[(size_t)p.x * FU + l];
        float wt = __int_as_float(p.y);
        acc.x = fmaf(wt, __uint_as_float(g << 16), acc.x);
        acc.y = fmaf(wt, __uint_as_float(g & 0xffff0000u), acc.y);
    }
    ((float2*)out)[(size_t)r * 64 + l] = acc;
}

// ---------------------------------------------------------------------------
// BN batch statistics: per-feature sum and sumsq over nodes (fp32 input).
// ---------------------------------------------------------------------------
__global__ __launch_bounds__(256) void bnstats_kernel(const float* __restrict__ H,
                                                      float* __restrict__ sums,
                                                      int nNodes) {
    int f = threadIdx.x & 127;
    int g = threadIdx.x >> 7;
    int stride = gridDim.x * 2;
    float s = 0.f, sq = 0.f;
    for (int n = blockIdx.x * 2 + g; n < nNodes; n += stride) {
        float v = H[(size_t)n * F + f];
        s += v;
        sq = fmaf(v, v, sq);
    }
    __shared__ float red[256];
    red[threadIdx.x] = s;
    __syncthreads();
    float sfull = 0.f;
    if (g == 0) sfull = red[f] + red[f + 128];
    __syncthreads();
    red[threadIdx.x] = sq;
    __syncthreads();
    if (g == 0) {
        float sqfull = red[f] + red[f + 128];
        atomicAdd(&sums[f], sfull);
        atomicAdd(&sums[128 + f], sqfull);
    }
}

// Fold mean/var/gamma/beta into per-feature scale a and shift c.
// Note: layer-1 bias b1 cancels exactly in BN (mean subtraction) -> unused.
__global__ void bnfinal_kernel(const float* __restrict__ sums,
                               const float* __restrict__ gamma,
                               const float* __restrict__ beta,
                               float* __restrict__ ac, float invN) {
    int f = threadIdx.x;
    float mean = sums[f] * invN;
    float var = sums[128 + f] * invN - mean * mean;
    float a = gamma[f] * rsqrtf(var + 1e-5f);
    ac[f] = a;
    ac[128 + f] = beta[f] - mean * a;
}

extern "C" void kernel_launch(void* const* d_in, const int* in_sizes, int n_in,
                              void* d_out, int out_size, void* d_ws, size_t ws_size,
                              hipStream_t stream) {
    const float* x    = (const float*)d_in[0];
    const int*   erow = (const int*)d_in[1];
    const int*   ecol = (const int*)d_in[2];
    const float* ew   = (const float*)d_in[3];
    const float* W1   = (const float*)d_in[4];
    // d_in[5] = b1: unused — cancels exactly under BatchNorm mean subtraction.
    const float* W2   = (const float*)d_in[6];
    const float* b2   = (const float*)d_in[7];
    const float* gmm  = (const float*)d_in[8];
    const float* beta = (const float*)d_in[9];
    float* out = (float*)d_out;

    const int N = in_sizes[0] / F;   // 100000
    const int E = in_sizes[1];       // 1600000

    const int NB = (N + RPB - 1) / RPB;     // 782  (<=1024 required)
    const int nT = (E + TILE - 1) / TILE;   // 782  (<=1024 required)

    // ---- workspace carve-up ----
    float*        buf1   = (float*)d_ws;                          // N*F fp32
    unsigned int* Hb     = (unsigned int*)(buf1 + (size_t)N * F); // N*FU bf16
    float*        stats  = (float*)(Hb + (size_t)N * FU);         // 256
    float*        ac     = stats + 256;                           // 256
    int*          rowptr = (int*)(ac + 256);                      // N+2
    int*          start  = rowptr + N + 2;                        // NB+1 -> 1028
    int*          total  = start + 1028;                          // 1024
    int*          hist   = total + 1024;                          // nT*NB
    int*          off    = hist + (size_t)nT * NB;                // NB*nT
    int2*         tmp    = (int2*)(off + (size_t)NB * nT);        // E
    int2*         pairs  = tmp + E;                               // E

    const int gemmGrid = (N + 31) / 32;
    const int spmmGrid = (N + 3) / 4;

    hipMemsetAsync(stats, 0, 256 * sizeof(float), stream);

    // ---- build CSR: deterministic bucket sort, shared by both layers ----
    histo_kernel<<<nT, 256, 0, stream>>>(erow, hist, NB, E);
    btot_kernel<<<NB, 256, 0, stream>>>(hist, total, nT, NB);
    bstart_kernel<<<1, 1024, 0, stream>>>(total, start, NB, E);
    boff_kernel<<<NB, 1024, 0, stream>>>(hist, start, off, nT, NB);
    bplace_kernel<<<nT, 256, 0, stream>>>(erow, ecol, ew, off, tmp, nT, NB, E);
    bsort_kernel<<<NB, 256, 0, stream>>>(tmp, start, pairs, rowptr, N, NB, E);

    // Layer 1: Hb = bf16(x @ W1) ; buf1 = A @ Hb
    gemm_kernel<false><<<gemmGrid, 256, 0, stream>>>(x, W1, nullptr, Hb, N);
    spmm_csr_kernel<<<spmmGrid, 256, 0, stream>>>(rowptr, pairs, Hb, nullptr, buf1, N);
    // BN stats + fold
    bnstats_kernel<<<400, 256, 0, stream>>>(buf1, stats, N);
    bnfinal_kernel<<<1, 128, 0, stream>>>(stats, gmm, beta, ac, 1.0f / (float)N);
    // Layer 2: Hb = bf16(relu(bn(buf1)) @ W2) ; out = A @ Hb + b2
    gemm_kernel<true><<<gemmGrid, 256, 0, stream>>>(buf1, W2, ac, Hb, N);
    spmm_csr_kernel<<<spmmGrid, 256, 0, stream>>>(rowptr, pairs, Hb, b2, out, N);
}

// Round 6
// 416.733 us; speedup vs baseline: 1.5512x; 1.2469x over previous
//
#include <hip/hip_runtime.h>

#define F    128
#define FQ   32    // F/4 (float4 per row)
#define FU   64    // uints per bf16 row
#define RPB  128   // rows per bucket
#define BSH  7     // log2(RPB)
#define TILE 2048  // edges per histogram tile (256 thr x 8)
#define SCAP 4096  // max edges per bucket section (mean 2046, +45 sigma)
#define LSTR 68    // LDS row stride in dwords (136 bf16): 16-B aligned, 2-way banks

typedef __attribute__((ext_vector_type(8))) short short8;   // MFMA A/B frag (8 bf16)
typedef __attribute__((ext_vector_type(4))) float f32x4;    // MFMA C/D frag

// pack two fp32 -> two bf16 (RNE) in one uint (a = low = even lane)
__device__ __forceinline__ unsigned int f2bf2(float a, float b) {
    unsigned int ua = __float_as_uint(a);
    unsigned int ub = __float_as_uint(b);
    ua = (ua + 0x7fffu + ((ua >> 16) & 1u)) >> 16;
    ub = (ub + 0x7fffu + ((ub >> 16) & 1u)) >> 16;
    return ua | (ub << 16);
}
__device__ __forceinline__ unsigned short f2bf1(float a) {
    unsigned int ua = __float_as_uint(a);
    return (unsigned short)((ua + 0x7fffu + ((ua >> 16) & 1u)) >> 16);
}

// ---------------------------------------------------------------------------
// MFMA GEMM: H[n][f] = sum_k In[n][k] * W[k][f], inputs converted to bf16 at
// LDS staging, fp32 accumulate, output packed bf16.
// If BN: input transformed as relu(a[k]*In[n][k] + c[k]) before conversion.
// Tile: 64 nodes x 128 feats, 256 threads (4 waves; wave w = feats 32w..32w+31).
// LDS: Xt[64][136] bf16 + Wt[128][136] bf16 (W transposed) = 52 KB -> 3 blk/CU.
// Frag layouts (guide m89/m91/m120): A[m=lane&15][k=quad*8+j],
// B[n=lane&15][k=quad*8+j] (from Wt rows), D col=lane&15 row=quad*4+reg.
// ---------------------------------------------------------------------------
template <bool BN>
__global__ __launch_bounds__(256) void gemm_kernel(const float* __restrict__ X,
                                                   const float* __restrict__ W,
                                                   const float* __restrict__ ac,
                                                   unsigned int* __restrict__ Hb,
                                                   int nNodes) {
    __shared__ unsigned int XtU[64 * LSTR];    // bf16 pairs: Xt[node][k]
    __shared__ unsigned int WtU[128 * LSTR];   // bf16 pairs: Wt[feat][k]

    const int tid = threadIdx.x;
    const int bn0 = blockIdx.x * 64;

    // ---- stage W transposed: thread t covers feat f=t>>1, k-half t&1 ----
    {
        int f = tid >> 1;
        int kh = (tid & 1) * 64;
        #pragma unroll
        for (int k8 = 0; k8 < 8; ++k8) {       // 8 k-values per iter
            int k0 = kh + k8 * 8;
            float v[8];
            #pragma unroll
            for (int i = 0; i < 8; ++i) v[i] = W[(size_t)(k0 + i) * F + f];
            uint4 pk;
            pk.x = f2bf2(v[0], v[1]);
            pk.y = f2bf2(v[2], v[3]);
            pk.z = f2bf2(v[4], v[5]);
            pk.w = f2bf2(v[6], v[7]);
            *(uint4*)&WtU[f * LSTR + k0 / 2] = pk;
        }
    }
    // ---- stage X tile (64 nodes x 128 k) as bf16, optional BN+ReLU ----
    {
        const float4* X4 = (const float4*)X;
        const float4* A4 = (const float4*)ac;
        const float4* C4 = (const float4*)(ac + F);
        #pragma unroll
        for (int it = 0; it < 8; ++it) {
            int i = tid + it * 256;            // 0..2047
            int n = i >> 5;                    // node 0..63
            int kq = i & 31;                   // float4 index 0..31
            int node = bn0 + n;
            float4 v = make_float4(0.f, 0.f, 0.f, 0.f);
            if (node < nNodes) v = X4[(size_t)node * FQ + kq];
            if (BN) {
                float4 a = A4[kq], c = C4[kq];
                v.x = fmaxf(fmaf(a.x, v.x, c.x), 0.f);
                v.y = fmaxf(fmaf(a.y, v.y, c.y), 0.f);
                v.z = fmaxf(fmaf(a.z, v.z, c.z), 0.f);
                v.w = fmaxf(fmaf(a.w, v.w, c.w), 0.f);
            }
            uint2 pk = make_uint2(f2bf2(v.x, v.y), f2bf2(v.z, v.w));
            *(uint2*)&XtU[n * LSTR + kq * 2] = pk;
        }
    }
    __syncthreads();

    // ---- MFMA compute ----
    const int l = tid & 63;
    const int wv = tid >> 6;
    const int quad = l >> 4, lo = l & 15;
    const int fb = wv * 32;

    f32x4 acc[4][2];
    #pragma unroll
    for (int nt = 0; nt < 4; ++nt)
        #pragma unroll
        for (int ft = 0; ft < 2; ++ft) acc[nt][ft] = (f32x4){0.f, 0.f, 0.f, 0.f};

    #pragma unroll
    for (int kc = 0; kc < 4; ++kc) {           // K chunks of 32
        int koff = kc * 16 + quad * 4;         // dword offset within row
        short8 a[4], b[2];
        #pragma unroll
        for (int nt = 0; nt < 4; ++nt)
            a[nt] = *(const short8*)&XtU[(nt * 16 + lo) * LSTR + koff];
        #pragma unroll
        for (int ft = 0; ft < 2; ++ft)
            b[ft] = *(const short8*)&WtU[(fb + ft * 16 + lo) * LSTR + koff];
        #pragma unroll
        for (int nt = 0; nt < 4; ++nt)
            #pragma unroll
            for (int ft = 0; ft < 2; ++ft)
                acc[nt][ft] = __builtin_amdgcn_mfma_f32_16x16x32_bf16(
                    a[nt], b[ft], acc[nt][ft], 0, 0, 0);
    }

    // ---- epilogue: bf16 store (D: col=lane&15, row=quad*4+reg) ----
    unsigned short* Hs = (unsigned short*)Hb;
    #pragma unroll
    for (int nt = 0; nt < 4; ++nt) {
        #pragma unroll
        for (int reg = 0; reg < 4; ++reg) {
            int node = bn0 + nt * 16 + quad * 4 + reg;
            if (node < nNodes) {
                #pragma unroll
                for (int ft = 0; ft < 2; ++ft)
                    Hs[(size_t)node * F + fb + ft * 16 + lo] = f2bf1(acc[nt][ft][reg]);
            }
        }
    }
}

// ---------------------------------------------------------------------------
// CSR build via deterministic bucket sort — NO returning global atomics.
// ---------------------------------------------------------------------------
__global__ __launch_bounds__(256) void histo_kernel(const int* __restrict__ row,
                                                    int* __restrict__ hist,
                                                    int NB, int E) {
    __shared__ int h[1024];
    int t = threadIdx.x;
    for (int i = t; i < NB; i += 256) h[i] = 0;
    __syncthreads();
    int base = blockIdx.x * TILE + t * 8;
    if (base + 7 < E) {
        int4 a = ((const int4*)row)[(base >> 2) + 0];
        int4 b = ((const int4*)row)[(base >> 2) + 1];
        atomicAdd(&h[a.x >> BSH], 1); atomicAdd(&h[a.y >> BSH], 1);
        atomicAdd(&h[a.z >> BSH], 1); atomicAdd(&h[a.w >> BSH], 1);
        atomicAdd(&h[b.x >> BSH], 1); atomicAdd(&h[b.y >> BSH], 1);
        atomicAdd(&h[b.z >> BSH], 1); atomicAdd(&h[b.w >> BSH], 1);
    } else {
        for (int j = 0; j < 8; ++j)
            if (base + j < E) atomicAdd(&h[row[base + j] >> BSH], 1);
    }
    __syncthreads();
    for (int i = t; i < NB; i += 256) hist[(size_t)blockIdx.x * NB + i] = h[i];
}

__global__ __launch_bounds__(256) void btot_kernel(const int* __restrict__ hist,
                                                   int* __restrict__ total,
                                                   int nT, int NB) {
    int b = blockIdx.x;
    int s = 0;
    for (int t = threadIdx.x; t < nT; t += 256) s += hist[(size_t)t * NB + b];
    __shared__ int red[256];
    red[threadIdx.x] = s;
    __syncthreads();
    for (int o = 128; o > 0; o >>= 1) {
        if (threadIdx.x < o) red[threadIdx.x] += red[threadIdx.x + o];
        __syncthreads();
    }
    if (threadIdx.x == 0) total[b] = red[0];
}

__global__ __launch_bounds__(1024) void bstart_kernel(const int* __restrict__ total,
                                                      int* __restrict__ start,
                                                      int NB, int E) {
    __shared__ int sh[1024];
    int t = threadIdx.x;
    int v = (t < NB) ? total[t] : 0;
    sh[t] = v;
    __syncthreads();
    #pragma unroll
    for (int o = 1; o < 1024; o <<= 1) {
        int add = (t >= o) ? sh[t - o] : 0;
        __syncthreads();
        sh[t] += add;
        __syncthreads();
    }
    if (t < NB) start[t] = sh[t] - v;
    if (t == 0) start[NB] = E;
}

__global__ __launch_bounds__(1024) void boff_kernel(const int* __restrict__ hist,
                                                    const int* __restrict__ start,
                                                    int* __restrict__ off,
                                                    int nT, int NB) {
    __shared__ int sh[1024];
    int b = blockIdx.x, t = threadIdx.x;
    int v = (t < nT) ? hist[(size_t)t * NB + b] : 0;
    sh[t] = v;
    __syncthreads();
    #pragma unroll
    for (int o = 1; o < 1024; o <<= 1) {
        int add = (t >= o) ? sh[t - o] : 0;
        __syncthreads();
        sh[t] += add;
        __syncthreads();
    }
    if (t < nT) off[(size_t)b * nT + t] = start[b] + sh[t] - v;
}

__global__ __launch_bounds__(256) void bplace_kernel(const int* __restrict__ row,
                                                     const int* __restrict__ col,
                                                     const float* __restrict__ w,
                                                     const int* __restrict__ off,
                                                     int2* __restrict__ tmp,
                                                     int nT, int NB, int E) {
    __shared__ int h[1024];
    int t = threadIdx.x, tile = blockIdx.x;
    for (int i = t; i < NB; i += 256) h[i] = 0;
    __syncthreads();
    int base = tile * TILE + t * 8;
    int r[8], c[8];
    float ww[8];
    int nv = 0;
    if (base + 7 < E) {
        int4 ra = ((const int4*)row)[(base >> 2) + 0];
        int4 rb = ((const int4*)row)[(base >> 2) + 1];
        int4 ca = ((const int4*)col)[(base >> 2) + 0];
        int4 cb = ((const int4*)col)[(base >> 2) + 1];
        float4 wa = ((const float4*)w)[(base >> 2) + 0];
        float4 wb = ((const float4*)w)[(base >> 2) + 1];
        r[0] = ra.x; r[1] = ra.y; r[2] = ra.z; r[3] = ra.w;
        r[4] = rb.x; r[5] = rb.y; r[6] = rb.z; r[7] = rb.w;
        c[0] = ca.x; c[1] = ca.y; c[2] = ca.z; c[3] = ca.w;
        c[4] = cb.x; c[5] = cb.y; c[6] = cb.z; c[7] = cb.w;
        ww[0] = wa.x; ww[1] = wa.y; ww[2] = wa.z; ww[3] = wa.w;
        ww[4] = wb.x; ww[5] = wb.y; ww[6] = wb.z; ww[7] = wb.w;
        nv = 8;
    } else {
        for (int j = 0; j < 8; ++j)
            if (base + j < E) { r[nv] = row[base + j]; c[nv] = col[base + j];
                                ww[nv] = w[base + j]; ++nv; }
    }
    #pragma unroll 8
    for (int j = 0; j < 8; ++j) {
        if (j >= nv) break;
        int b = r[j] >> BSH;
        int rank = atomicAdd(&h[b], 1);
        int pos = off[(size_t)b * nT + tile] + rank;
        tmp[pos] = make_int2(((r[j] & (RPB - 1)) << 25) | c[j], __float_as_int(ww[j]));
    }
}

__global__ __launch_bounds__(256) void bsort_kernel(const int2* __restrict__ tmp,
                                                    const int* __restrict__ start,
                                                    int2* __restrict__ pairs,
                                                    int* __restrict__ rowptr,
                                                    int N, int NB, int E) {
    __shared__ int cntB[RPB];
    __shared__ int cntS[RPB];
    __shared__ int sc[RPB];
    __shared__ int2 outP[SCAP];
    int b = blockIdx.x, t = threadIdx.x;
    int s0 = start[b], s1 = start[b + 1];
    int len = s1 - s0;
    if (len > SCAP) len = SCAP;

    if (t < RPB) cntB[t] = 0;
    __syncthreads();

    int2 p[16];
    int np = 0;
    #pragma unroll
    for (int k = 0; k < 16; ++k) {
        int i = t + k * 256;
        if (i < len) { p[k] = tmp[s0 + i]; ++np; }
    }
    #pragma unroll
    for (int k = 0; k < 16; ++k) {
        if (k >= np) break;
        atomicAdd(&cntB[((unsigned)p[k].x) >> 25], 1);
    }
    __syncthreads();
    int val = (t < RPB) ? cntB[t] : 0;
    if (t < RPB) sc[t] = val;
    __syncthreads();
    #pragma unroll
    for (int o = 1; o < RPB; o <<= 1) {
        int add = (t < RPB && t >= o) ? sc[t - o] : 0;
        __syncthreads();
        if (t < RPB) sc[t] += add;
        __syncthreads();
    }
    if (t < RPB) { int ex = sc[t] - val; cntB[t] = ex; cntS[t] = ex; }
    __syncthreads();
    #pragma unroll
    for (int k = 0; k < 16; ++k) {
        if (k >= np) break;
        int rl = ((unsigned)p[k].x) >> 25;
        int lr = atomicAdd(&cntB[rl], 1);
        outP[lr] = make_int2(p[k].x & 0x1ffffff, p[k].y);
    }
    __syncthreads();
    for (int i = t; i < len; i += 256) pairs[s0 + i] = outP[i];
    int r0 = b * RPB;
    if (t < RPB && r0 + t < N) rowptr[r0 + t] = s0 + cntS[t];
    if (b == NB - 1 && t == 0) rowptr[N] = E;
}

// ---------------------------------------------------------------------------
// CSR SpMM, bf16 gather operand: one wave per row, lane l covers feats 2l,2l+1.
// ---------------------------------------------------------------------------
__global__ __launch_bounds__(256) void spmm_csr_kernel(const int* __restrict__ rowptr,
                                                       const int2* __restrict__ pairs,
                                                       const unsigned int* __restrict__ Hb,
                                                       const float* __restrict__ bias,
                                                       float* __restrict__ out, int N) {
    int r = blockIdx.x * 4 + (threadIdx.x >> 6);
    if (r >= N) return;
    int l = threadIdx.x & 63;
    float2 acc = bias ? ((const float2*)bias)[l] : make_float2(0.f, 0.f);
    int i = rowptr[r], end = rowptr[r + 1];

    for (; i + 16 <= end; i += 16) {
        int2 p[16];
        #pragma unroll
        for (int j = 0; j < 16; ++j) p[j] = pairs[i + j];
        unsigned int g[16];
        #pragma unroll
        for (int j = 0; j < 16; ++j) g[j] = Hb[(size_t)p[j].x * FU + l];
        #pragma unroll
        for (int j = 0; j < 16; ++j) {
            float wt = __int_as_float(p[j].y);
            acc.x = fmaf(wt, __uint_as_float(g[j] << 16), acc.x);
            acc.y = fmaf(wt, __uint_as_float(g[j] & 0xffff0000u), acc.y);
        }
    }
    if (i + 8 <= end) {
        int2 p[8];
        #pragma unroll
        for (int j = 0; j < 8; ++j) p[j] = pairs[i + j];
        unsigned int g[8];
        #pragma unroll
        for (int j = 0; j < 8; ++j) g[j] = Hb[(size_t)p[j].x * FU + l];
        #pragma unroll
        for (int j = 0; j < 8; ++j) {
            float wt = __int_as_float(p[j].y);
            acc.x = fmaf(wt, __uint_as_float(g[j] << 16), acc.x);
            acc.y = fmaf(wt, __uint_as_float(g[j] & 0xffff0000u), acc.y);
        }
        i += 8;
    }
    if (i + 4 <= end) {
        int2 p[4];
        #pragma unroll
        for (int j = 0; j < 4; ++j) p[j] = pairs[i + j];
        unsigned int g[4];
        #pragma unroll
        for (int j = 0; j < 4; ++j) g[j] = Hb[(size_t)p[j].x * FU + l];
        #pragma unroll
        for (int j = 0; j < 4; ++j) {
            float wt = __int_as_float(p[j].y);
            acc.x = fmaf(wt, __uint_as_float(g[j] << 16), acc.x);
            acc.y = fmaf(wt, __uint_as_float(g[j] & 0xffff0000u), acc.y);
        }
        i += 4;
    }
    for (; i < end; ++i) {
        int2 p = pairs[i];
        unsigned int g = Hb[(size_t)p.x * FU + l];
        float wt = __int_as_float(p.y);
        acc.x = fmaf(wt, __uint_as_float(g << 16), acc.x);
        acc.y = fmaf(wt, __uint_as_float(g & 0xffff0000u), acc.y);
    }
    ((float2*)out)[(size_t)r * 64 + l] = acc;
}

// ---------------------------------------------------------------------------
// BN batch statistics + fold.
// ---------------------------------------------------------------------------
__global__ __launch_bounds__(256) void bnstats_kernel(const float* __restrict__ H,
                                                      float* __restrict__ sums,
                                                      int nNodes) {
    int f = threadIdx.x & 127;
    int g = threadIdx.x >> 7;
    int stride = gridDim.x * 2;
    float s = 0.f, sq = 0.f;
    for (int n = blockIdx.x * 2 + g; n < nNodes; n += stride) {
        float v = H[(size_t)n * F + f];
        s += v;
        sq = fmaf(v, v, sq);
    }
    __shared__ float red[256];
    red[threadIdx.x] = s;
    __syncthreads();
    float sfull = 0.f;
    if (g == 0) sfull = red[f] + red[f + 128];
    __syncthreads();
    red[threadIdx.x] = sq;
    __syncthreads();
    if (g == 0) {
        float sqfull = red[f] + red[f + 128];
        atomicAdd(&sums[f], sfull);
        atomicAdd(&sums[128 + f], sqfull);
    }
}

// Note: layer-1 bias b1 cancels exactly in BN (mean subtraction) -> unused.
__global__ void bnfinal_kernel(const float* __restrict__ sums,
                               const float* __restrict__ gamma,
                               const float* __restrict__ beta,
                               float* __restrict__ ac, float invN) {
    int f = threadIdx.x;
    float mean = sums[f] * invN;
    float var = sums[128 + f] * invN - mean * mean;
    float a = gamma[f] * rsqrtf(var + 1e-5f);
    ac[f] = a;
    ac[128 + f] = beta[f] - mean * a;
}

extern "C" void kernel_launch(void* const* d_in, const int* in_sizes, int n_in,
                              void* d_out, int out_size, void* d_ws, size_t ws_size,
                              hipStream_t stream) {
    const float* x    = (const float*)d_in[0];
    const int*   erow = (const int*)d_in[1];
    const int*   ecol = (const int*)d_in[2];
    const float* ew   = (const float*)d_in[3];
    const float* W1   = (const float*)d_in[4];
    // d_in[5] = b1: unused — cancels exactly under BatchNorm mean subtraction.
    const float* W2   = (const float*)d_in[6];
    const float* b2   = (const float*)d_in[7];
    const float* gmm  = (const float*)d_in[8];
    const float* beta = (const float*)d_in[9];
    float* out = (float*)d_out;

    const int N = in_sizes[0] / F;   // 100000
    const int E = in_sizes[1];       // 1600000

    const int NB = (N + RPB - 1) / RPB;     // 782
    const int nT = (E + TILE - 1) / TILE;   // 782

    // ---- workspace carve-up ----
    float*        buf1   = (float*)d_ws;                          // N*F fp32
    unsigned int* Hb     = (unsigned int*)(buf1 + (size_t)N * F); // N*FU bf16
    float*        stats  = (float*)(Hb + (size_t)N * FU);         // 256
    float*        ac     = stats + 256;                           // 256
    int*          rowptr = (int*)(ac + 256);                      // N+2
    int*          start  = rowptr + N + 2;                        // 1028
    int*          total  = start + 1028;                          // 1024
    int*          hist   = total + 1024;                          // nT*NB
    int*          off    = hist + (size_t)nT * NB;                // NB*nT
    int2*         tmp    = (int2*)(off + (size_t)NB * nT);        // E
    int2*         pairs  = tmp + E;                               // E

    const int gemmGrid = (N + 63) / 64;
    const int spmmGrid = (N + 3) / 4;

    hipMemsetAsync(stats, 0, 256 * sizeof(float), stream);

    // ---- build CSR: deterministic bucket sort, shared by both layers ----
    histo_kernel<<<nT, 256, 0, stream>>>(erow, hist, NB, E);
    btot_kernel<<<NB, 256, 0, stream>>>(hist, total, nT, NB);
    bstart_kernel<<<1, 1024, 0, stream>>>(total, start, NB, E);
    boff_kernel<<<NB, 1024, 0, stream>>>(hist, start, off, nT, NB);
    bplace_kernel<<<nT, 256, 0, stream>>>(erow, ecol, ew, off, tmp, nT, NB, E);
    bsort_kernel<<<NB, 256, 0, stream>>>(tmp, start, pairs, rowptr, N, NB, E);

    // Layer 1: Hb = bf16(x @ W1) ; buf1 = A @ Hb
    gemm_kernel<false><<<gemmGrid, 256, 0, stream>>>(x, W1, nullptr, Hb, N);
    spmm_csr_kernel<<<spmmGrid, 256, 0, stream>>>(rowptr, pairs, Hb, nullptr, buf1, N);
    // BN stats + fold
    bnstats_kernel<<<400, 256, 0, stream>>>(buf1, stats, N);
    bnfinal_kernel<<<1, 128, 0, stream>>>(stats, gmm, beta, ac, 1.0f / (float)N);
    // Layer 2: Hb = bf16(relu(bn(buf1)) @ W2) ; out = A @ Hb + b2
    gemm_kernel<true><<<gemmGrid, 256, 0, stream>>>(buf1, W2, ac, Hb, N);
    spmm_csr_kernel<<<spmmGrid, 256, 0, stream>>>(rowptr, pairs, Hb, b2, out, N);
}

// Round 7
// 398.507 us; speedup vs baseline: 1.6221x; 1.0457x over previous
//
#include <hip/hip_runtime.h>

#define F    128
#define FQ   32    // F/4 (float4 per row)
#define FU   64    // uints per bf16 row
#define RPB  128   // rows per bucket
#define BSH  7     // log2(RPB)
#define TILE 2048  // edges per histogram tile (256 thr x 8)
#define SCAP 4096  // max edges per bucket section (mean 2046, +45 sigma)
#define LSTR 68    // LDS row stride in dwords (136 bf16): 16-B aligned, 2-way banks

typedef __attribute__((ext_vector_type(8))) short short8;   // MFMA A/B frag (8 bf16)
typedef __attribute__((ext_vector_type(4))) float f32x4;    // MFMA C/D frag

// pack two fp32 -> two bf16 (RNE) in one uint (a = low = even feature)
__device__ __forceinline__ unsigned int f2bf2(float a, float b) {
    unsigned int ua = __float_as_uint(a);
    unsigned int ub = __float_as_uint(b);
    ua = (ua + 0x7fffu + ((ua >> 16) & 1u)) >> 16;
    ub = (ub + 0x7fffu + ((ub >> 16) & 1u)) >> 16;
    return ua | (ub << 16);
}
__device__ __forceinline__ unsigned short f2bf1(float a) {
    unsigned int ua = __float_as_uint(a);
    return (unsigned short)((ua + 0x7fffu + ((ua >> 16) & 1u)) >> 16);
}

// ---------------------------------------------------------------------------
// MFMA GEMM: H[n][f] = sum_k In[n][k] * W[k][f] -> packed bf16.
// BN=false: X is fp32 [N][128].  BN=true: X is packed bf16 [N][64 uints],
// transformed relu(a[k]*x+c[k]) at staging.
// Tile: 64 nodes x 128 feats, 256 threads; LDS Xt[64]+Wt[128] rows (bf16,
// stride 136 = 2-way bank aliasing, free per m136). 52 KB -> 3 blocks/CU.
// ---------------------------------------------------------------------------
template <bool BN>
__global__ __launch_bounds__(256) void gemm_kernel(const void* __restrict__ Xv,
                                                   const float* __restrict__ W,
                                                   const float* __restrict__ ac,
                                                   unsigned int* __restrict__ Hb,
                                                   int nNodes) {
    __shared__ unsigned int XtU[64 * LSTR];    // bf16 pairs: Xt[node][k]
    __shared__ unsigned int WtU[128 * LSTR];   // bf16 pairs: Wt[feat][k]

    const int tid = threadIdx.x;
    const int bn0 = blockIdx.x * 64;

    // ---- stage W transposed ----
    {
        int f = tid >> 1;
        int kh = (tid & 1) * 64;
        #pragma unroll
        for (int k8 = 0; k8 < 8; ++k8) {
            int k0 = kh + k8 * 8;
            float v[8];
            #pragma unroll
            for (int i = 0; i < 8; ++i) v[i] = W[(size_t)(k0 + i) * F + f];
            uint4 pk;
            pk.x = f2bf2(v[0], v[1]);
            pk.y = f2bf2(v[2], v[3]);
            pk.z = f2bf2(v[4], v[5]);
            pk.w = f2bf2(v[6], v[7]);
            *(uint4*)&WtU[f * LSTR + k0 / 2] = pk;
        }
    }
    // ---- stage X tile as bf16, optional BN+ReLU ----
    {
        const float4* A4 = (const float4*)ac;
        const float4* C4 = (const float4*)(ac + F);
        #pragma unroll
        for (int it = 0; it < 8; ++it) {
            int i = tid + it * 256;            // 0..2047
            int n = i >> 5;                    // node 0..63
            int kq = i & 31;                   // 4-feat group 0..31
            int node = bn0 + n;
            uint2 pk = make_uint2(0u, 0u);
            if (BN) {
                uint2 raw = make_uint2(0u, 0u);
                if (node < nNodes) raw = ((const uint2*)Xv)[(size_t)node * 32 + kq];
                float4 v;
                v.x = __uint_as_float(raw.x << 16);
                v.y = __uint_as_float(raw.x & 0xffff0000u);
                v.z = __uint_as_float(raw.y << 16);
                v.w = __uint_as_float(raw.y & 0xffff0000u);
                float4 a = A4[kq], c = C4[kq];
                v.x = fmaxf(fmaf(a.x, v.x, c.x), 0.f);
                v.y = fmaxf(fmaf(a.y, v.y, c.y), 0.f);
                v.z = fmaxf(fmaf(a.z, v.z, c.z), 0.f);
                v.w = fmaxf(fmaf(a.w, v.w, c.w), 0.f);
                pk = make_uint2(f2bf2(v.x, v.y), f2bf2(v.z, v.w));
            } else {
                float4 v = make_float4(0.f, 0.f, 0.f, 0.f);
                if (node < nNodes) v = ((const float4*)Xv)[(size_t)node * FQ + kq];
                pk = make_uint2(f2bf2(v.x, v.y), f2bf2(v.z, v.w));
            }
            *(uint2*)&XtU[n * LSTR + kq * 2] = pk;
        }
    }
    __syncthreads();

    // ---- MFMA compute ----
    const int l = tid & 63;
    const int wv = tid >> 6;
    const int quad = l >> 4, lo = l & 15;
    const int fb = wv * 32;

    f32x4 acc[4][2];
    #pragma unroll
    for (int nt = 0; nt < 4; ++nt)
        #pragma unroll
        for (int ft = 0; ft < 2; ++ft) acc[nt][ft] = (f32x4){0.f, 0.f, 0.f, 0.f};

    #pragma unroll
    for (int kc = 0; kc < 4; ++kc) {
        int koff = kc * 16 + quad * 4;
        short8 a[4], b[2];
        #pragma unroll
        for (int nt = 0; nt < 4; ++nt)
            a[nt] = *(const short8*)&XtU[(nt * 16 + lo) * LSTR + koff];
        #pragma unroll
        for (int ft = 0; ft < 2; ++ft)
            b[ft] = *(const short8*)&WtU[(fb + ft * 16 + lo) * LSTR + koff];
        #pragma unroll
        for (int nt = 0; nt < 4; ++nt)
            #pragma unroll
            for (int ft = 0; ft < 2; ++ft)
                acc[nt][ft] = __builtin_amdgcn_mfma_f32_16x16x32_bf16(
                    a[nt], b[ft], acc[nt][ft], 0, 0, 0);
    }

    // ---- epilogue: bf16 store (D: col=lane&15, row=quad*4+reg) ----
    unsigned short* Hs = (unsigned short*)Hb;
    #pragma unroll
    for (int nt = 0; nt < 4; ++nt) {
        #pragma unroll
        for (int reg = 0; reg < 4; ++reg) {
            int node = bn0 + nt * 16 + quad * 4 + reg;
            if (node < nNodes) {
                #pragma unroll
                for (int ft = 0; ft < 2; ++ft)
                    Hs[(size_t)node * F + fb + ft * 16 + lo] = f2bf1(acc[nt][ft][reg]);
            }
        }
    }
}

// ---------------------------------------------------------------------------
// CSR build via deterministic bucket sort — NO returning global atomics.
// ---------------------------------------------------------------------------
__global__ __launch_bounds__(256) void histo_kernel(const int* __restrict__ row,
                                                    int* __restrict__ hist,
                                                    int NB, int E) {
    __shared__ int h[1024];
    int t = threadIdx.x;
    for (int i = t; i < NB; i += 256) h[i] = 0;
    __syncthreads();
    int base = blockIdx.x * TILE + t * 8;
    if (base + 7 < E) {
        int4 a = ((const int4*)row)[(base >> 2) + 0];
        int4 b = ((const int4*)row)[(base >> 2) + 1];
        atomicAdd(&h[a.x >> BSH], 1); atomicAdd(&h[a.y >> BSH], 1);
        atomicAdd(&h[a.z >> BSH], 1); atomicAdd(&h[a.w >> BSH], 1);
        atomicAdd(&h[b.x >> BSH], 1); atomicAdd(&h[b.y >> BSH], 1);
        atomicAdd(&h[b.z >> BSH], 1); atomicAdd(&h[b.w >> BSH], 1);
    } else {
        for (int j = 0; j < 8; ++j)
            if (base + j < E) atomicAdd(&h[row[base + j] >> BSH], 1);
    }
    __syncthreads();
    for (int i = t; i < NB; i += 256) hist[(size_t)blockIdx.x * NB + i] = h[i];
}

__global__ __launch_bounds__(256) void btot_kernel(const int* __restrict__ hist,
                                                   int* __restrict__ total,
                                                   int nT, int NB) {
    int b = blockIdx.x;
    int s = 0;
    for (int t = threadIdx.x; t < nT; t += 256) s += hist[(size_t)t * NB + b];
    __shared__ int red[256];
    red[threadIdx.x] = s;
    __syncthreads();
    for (int o = 128; o > 0; o >>= 1) {
        if (threadIdx.x < o) red[threadIdx.x] += red[threadIdx.x + o];
        __syncthreads();
    }
    if (threadIdx.x == 0) total[b] = red[0];
}

__global__ __launch_bounds__(1024) void bstart_kernel(const int* __restrict__ total,
                                                      int* __restrict__ start,
                                                      int NB, int E) {
    __shared__ int sh[1024];
    int t = threadIdx.x;
    int v = (t < NB) ? total[t] : 0;
    sh[t] = v;
    __syncthreads();
    #pragma unroll
    for (int o = 1; o < 1024; o <<= 1) {
        int add = (t >= o) ? sh[t - o] : 0;
        __syncthreads();
        sh[t] += add;
        __syncthreads();
    }
    if (t < NB) start[t] = sh[t] - v;
    if (t == 0) start[NB] = E;
}

__global__ __launch_bounds__(1024) void boff_kernel(const int* __restrict__ hist,
                                                    const int* __restrict__ start,
                                                    int* __restrict__ off,
                                                    int nT, int NB) {
    __shared__ int sh[1024];
    int b = blockIdx.x, t = threadIdx.x;
    int v = (t < nT) ? hist[(size_t)t * NB + b] : 0;
    sh[t] = v;
    __syncthreads();
    #pragma unroll
    for (int o = 1; o < 1024; o <<= 1) {
        int add = (t >= o) ? sh[t - o] : 0;
        __syncthreads();
        sh[t] += add;
        __syncthreads();
    }
    if (t < nT) off[(size_t)b * nT + t] = start[b] + sh[t] - v;
}

__global__ __launch_bounds__(256) void bplace_kernel(const int* __restrict__ row,
                                                     const int* __restrict__ col,
                                                     const float* __restrict__ w,
                                                     const int* __restrict__ off,
                                                     int2* __restrict__ tmp,
                                                     int nT, int NB, int E) {
    __shared__ int h[1024];
    int t = threadIdx.x, tile = blockIdx.x;
    for (int i = t; i < NB; i += 256) h[i] = 0;
    __syncthreads();
    int base = tile * TILE + t * 8;
    int r[8], c[8];
    float ww[8];
    int nv = 0;
    if (base + 7 < E) {
        int4 ra = ((const int4*)row)[(base >> 2) + 0];
        int4 rb = ((const int4*)row)[(base >> 2) + 1];
        int4 ca = ((const int4*)col)[(base >> 2) + 0];
        int4 cb = ((const int4*)col)[(base >> 2) + 1];
        float4 wa = ((const float4*)w)[(base >> 2) + 0];
        float4 wb = ((const float4*)w)[(base >> 2) + 1];
        r[0] = ra.x; r[1] = ra.y; r[2] = ra.z; r[3] = ra.w;
        r[4] = rb.x; r[5] = rb.y; r[6] = rb.z; r[7] = rb.w;
        c[0] = ca.x; c[1] = ca.y; c[2] = ca.z; c[3] = ca.w;
        c[4] = cb.x; c[5] = cb.y; c[6] = cb.z; c[7] = cb.w;
        ww[0] = wa.x; ww[1] = wa.y; ww[2] = wa.z; ww[3] = wa.w;
        ww[4] = wb.x; ww[5] = wb.y; ww[6] = wb.z; ww[7] = wb.w;
        nv = 8;
    } else {
        for (int j = 0; j < 8; ++j)
            if (base + j < E) { r[nv] = row[base + j]; c[nv] = col[base + j];
                                ww[nv] = w[base + j]; ++nv; }
    }
    #pragma unroll 8
    for (int j = 0; j < 8; ++j) {
        if (j >= nv) break;
        int b = r[j] >> BSH;
        int rank = atomicAdd(&h[b], 1);
        int pos = off[(size_t)b * nT + tile] + rank;
        tmp[pos] = make_int2(((r[j] & (RPB - 1)) << 25) | c[j], __float_as_int(ww[j]));
    }
}

__global__ __launch_bounds__(256) void bsort_kernel(const int2* __restrict__ tmp,
                                                    const int* __restrict__ start,
                                                    int2* __restrict__ pairs,
                                                    int* __restrict__ rowptr,
                                                    int N, int NB, int E) {
    __shared__ int cntB[RPB];
    __shared__ int cntS[RPB];
    __shared__ int sc[RPB];
    __shared__ int2 outP[SCAP];
    int b = blockIdx.x, t = threadIdx.x;
    int s0 = start[b], s1 = start[b + 1];
    int len = s1 - s0;
    if (len > SCAP) len = SCAP;

    if (t < RPB) cntB[t] = 0;
    __syncthreads();

    int2 p[16];
    int np = 0;
    #pragma unroll
    for (int k = 0; k < 16; ++k) {
        int i = t + k * 256;
        if (i < len) { p[k] = tmp[s0 + i]; ++np; }
    }
    #pragma unroll
    for (int k = 0; k < 16; ++k) {
        if (k >= np) break;
        atomicAdd(&cntB[((unsigned)p[k].x) >> 25], 1);
    }
    __syncthreads();
    int val = (t < RPB) ? cntB[t] : 0;
    if (t < RPB) sc[t] = val;
    __syncthreads();
    #pragma unroll
    for (int o = 1; o < RPB; o <<= 1) {
        int add = (t < RPB && t >= o) ? sc[t - o] : 0;
        __syncthreads();
        if (t < RPB) sc[t] += add;
        __syncthreads();
    }
    if (t < RPB) { int ex = sc[t] - val; cntB[t] = ex; cntS[t] = ex; }
    __syncthreads();
    #pragma unroll
    for (int k = 0; k < 16; ++k) {
        if (k >= np) break;
        int rl = ((unsigned)p[k].x) >> 25;
        int lr = atomicAdd(&cntB[rl], 1);
        outP[lr] = make_int2(p[k].x & 0x1ffffff, p[k].y);
    }
    __syncthreads();
    for (int i = t; i < len; i += 256) pairs[s0 + i] = outP[i];
    int r0 = b * RPB;
    if (t < RPB && r0 + t < N) rowptr[r0 + t] = s0 + cntS[t];
    if (b == NB - 1 && t == 0) rowptr[N] = E;
}

// ---------------------------------------------------------------------------
// CSR SpMM, bf16 gather, 16-B/lane: one wave per row; lane groups of 16 handle
// 4 edges concurrently (uint4 = 8 feats per lane); shfl_xor reduction at end.
// BF16OUT: packs result to bf16 (layer 1); else fp32 (final output).
// ---------------------------------------------------------------------------
template <bool BF16OUT>
__global__ __launch_bounds__(256) void spmm_csr_kernel(const int* __restrict__ rowptr,
                                                       const int2* __restrict__ pairs,
                                                       const unsigned int* __restrict__ Hb,
                                                       const float* __restrict__ bias,
                                                       void* __restrict__ outv, int N) {
    int r = blockIdx.x * 4 + (threadIdx.x >> 6);
    if (r >= N) return;
    const int l = threadIdx.x & 63;
    const int g = l >> 4, q = l & 15;          // edge subgroup, 8-feat chunk
    const uint4* H4 = (const uint4*)Hb;        // row = 16 uint4

    float acc[8];
    #pragma unroll
    for (int j = 0; j < 8; ++j) acc[j] = 0.f;

    int i = rowptr[r], end = rowptr[r + 1];

    for (; i + 16 <= end; i += 16) {
        int2 p[4];
        uint4 gv[4];
        #pragma unroll
        for (int k = 0; k < 4; ++k) p[k] = pairs[i + 4 * k + g];
        #pragma unroll
        for (int k = 0; k < 4; ++k) gv[k] = H4[(size_t)p[k].x * 16 + q];
        #pragma unroll
        for (int k = 0; k < 4; ++k) {
            float wt = __int_as_float(p[k].y);
            unsigned int uu[4] = {gv[k].x, gv[k].y, gv[k].z, gv[k].w};
            #pragma unroll
            for (int j = 0; j < 4; ++j) {
                acc[2 * j]     = fmaf(wt, __uint_as_float(uu[j] << 16), acc[2 * j]);
                acc[2 * j + 1] = fmaf(wt, __uint_as_float(uu[j] & 0xffff0000u), acc[2 * j + 1]);
            }
        }
    }
    for (; i + 4 <= end; i += 4) {
        int2 p = pairs[i + g];
        uint4 gv = H4[(size_t)p.x * 16 + q];
        float wt = __int_as_float(p.y);
        unsigned int uu[4] = {gv.x, gv.y, gv.z, gv.w};
        #pragma unroll
        for (int j = 0; j < 4; ++j) {
            acc[2 * j]     = fmaf(wt, __uint_as_float(uu[j] << 16), acc[2 * j]);
            acc[2 * j + 1] = fmaf(wt, __uint_as_float(uu[j] & 0xffff0000u), acc[2 * j + 1]);
        }
    }
    if (i < end) {
        int e = i + g;
        int2 p = (e < end) ? pairs[e] : make_int2(0, 0);   // wt=0 for pad lanes
        uint4 gv = H4[(size_t)p.x * 16 + q];
        float wt = __int_as_float(p.y);
        unsigned int uu[4] = {gv.x, gv.y, gv.z, gv.w};
        #pragma unroll
        for (int j = 0; j < 4; ++j) {
            acc[2 * j]     = fmaf(wt, __uint_as_float(uu[j] << 16), acc[2 * j]);
            acc[2 * j + 1] = fmaf(wt, __uint_as_float(uu[j] & 0xffff0000u), acc[2 * j + 1]);
        }
    }

    // reduce the 4 edge-subgroups (lanes q, q+16, q+32, q+48)
    #pragma unroll
    for (int j = 0; j < 8; ++j) {
        acc[j] += __shfl_xor(acc[j], 16, 64);
        acc[j] += __shfl_xor(acc[j], 32, 64);
    }

    if (g == 0) {
        if (bias) {
            float4 b0 = ((const float4*)bias)[q * 2];
            float4 b1 = ((const float4*)bias)[q * 2 + 1];
            acc[0] += b0.x; acc[1] += b0.y; acc[2] += b0.z; acc[3] += b0.w;
            acc[4] += b1.x; acc[5] += b1.y; acc[6] += b1.z; acc[7] += b1.w;
        }
        if (BF16OUT) {
            uint4 pk;
            pk.x = f2bf2(acc[0], acc[1]);
            pk.y = f2bf2(acc[2], acc[3]);
            pk.z = f2bf2(acc[4], acc[5]);
            pk.w = f2bf2(acc[6], acc[7]);
            ((uint4*)outv)[(size_t)r * 16 + q] = pk;
        } else {
            float4* o = (float4*)outv;
            o[(size_t)r * 32 + q * 2]     = make_float4(acc[0], acc[1], acc[2], acc[3]);
            o[(size_t)r * 32 + q * 2 + 1] = make_float4(acc[4], acc[5], acc[6], acc[7]);
        }
    }
}

// ---------------------------------------------------------------------------
// BN batch statistics over packed-bf16 input: per-feature sum and sumsq.
// ---------------------------------------------------------------------------
__global__ __launch_bounds__(256) void bnstats_kernel(const unsigned int* __restrict__ Hu,
                                                      float* __restrict__ sums,
                                                      int nNodes) {
    int u = threadIdx.x & 63;   // uint index: feats 2u, 2u+1
    int g = threadIdx.x >> 6;   // 0..3
    int stride = gridDim.x * 4;
    float s0 = 0.f, s1 = 0.f, q0 = 0.f, q1 = 0.f;
    for (int n = blockIdx.x * 4 + g; n < nNodes; n += stride) {
        unsigned int v = Hu[(size_t)n * FU + u];
        float a = __uint_as_float(v << 16);
        float b = __uint_as_float(v & 0xffff0000u);
        s0 += a; s1 += b;
        q0 = fmaf(a, a, q0); q1 = fmaf(b, b, q1);
    }
    __shared__ float4 red[256];
    red[threadIdx.x] = make_float4(s0, s1, q0, q1);
    __syncthreads();
    if (g == 0) {
        float4 r0 = red[u], r1 = red[64 + u], r2 = red[128 + u], r3 = red[192 + u];
        atomicAdd(&sums[2 * u],       r0.x + r1.x + r2.x + r3.x);
        atomicAdd(&sums[2 * u + 1],   r0.y + r1.y + r2.y + r3.y);
        atomicAdd(&sums[128 + 2 * u],     r0.z + r1.z + r2.z + r3.z);
        atomicAdd(&sums[128 + 2 * u + 1], r0.w + r1.w + r2.w + r3.w);
    }
}

// Note: layer-1 bias b1 cancels exactly in BN (mean subtraction) -> unused.
__global__ void bnfinal_kernel(const float* __restrict__ sums,
                               const float* __restrict__ gamma,
                               const float* __restrict__ beta,
                               float* __restrict__ ac, float invN) {
    int f = threadIdx.x;
    float mean = sums[f] * invN;
    float var = sums[128 + f] * invN - mean * mean;
    float a = gamma[f] * rsqrtf(var + 1e-5f);
    ac[f] = a;
    ac[128 + f] = beta[f] - mean * a;
}

extern "C" void kernel_launch(void* const* d_in, const int* in_sizes, int n_in,
                              void* d_out, int out_size, void* d_ws, size_t ws_size,
                              hipStream_t stream) {
    const float* x    = (const float*)d_in[0];
    const int*   erow = (const int*)d_in[1];
    const int*   ecol = (const int*)d_in[2];
    const float* ew   = (const float*)d_in[3];
    const float* W1   = (const float*)d_in[4];
    // d_in[5] = b1: unused — cancels exactly under BatchNorm mean subtraction.
    const float* W2   = (const float*)d_in[6];
    const float* b2   = (const float*)d_in[7];
    const float* gmm  = (const float*)d_in[8];
    const float* beta = (const float*)d_in[9];
    float* out = (float*)d_out;

    const int N = in_sizes[0] / F;   // 100000
    const int E = in_sizes[1];       // 1600000

    const int NB = (N + RPB - 1) / RPB;     // 782
    const int nT = (E + TILE - 1) / TILE;   // 782

    // ---- workspace carve-up ----
    unsigned int* buf1   = (unsigned int*)d_ws;                   // N*FU bf16 (h1)
    unsigned int* Hb     = buf1 + (size_t)N * FU;                 // N*FU bf16 (h0/h2)
    float*        stats  = (float*)(Hb + (size_t)N * FU);         // 256
    float*        ac     = stats + 256;                           // 256
    int*          rowptr = (int*)(ac + 256);                      // N+2
    int*          start  = rowptr + N + 2;                        // 1028
    int*          total  = start + 1028;                          // 1024
    int*          hist   = total + 1024;                          // nT*NB
    int*          off    = hist + (size_t)nT * NB;                // NB*nT
    int2*         tmp    = (int2*)(off + (size_t)NB * nT);        // E
    int2*         pairs  = tmp + E;                               // E

    const int gemmGrid = (N + 63) / 64;
    const int spmmGrid = (N + 3) / 4;

    hipMemsetAsync(stats, 0, 256 * sizeof(float), stream);

    // ---- build CSR: deterministic bucket sort, shared by both layers ----
    histo_kernel<<<nT, 256, 0, stream>>>(erow, hist, NB, E);
    btot_kernel<<<NB, 256, 0, stream>>>(hist, total, nT, NB);
    bstart_kernel<<<1, 1024, 0, stream>>>(total, start, NB, E);
    boff_kernel<<<NB, 1024, 0, stream>>>(hist, start, off, nT, NB);
    bplace_kernel<<<nT, 256, 0, stream>>>(erow, ecol, ew, off, tmp, nT, NB, E);
    bsort_kernel<<<NB, 256, 0, stream>>>(tmp, start, pairs, rowptr, N, NB, E);

    // Layer 1: Hb = bf16(x @ W1) ; buf1 = bf16(A @ Hb)
    gemm_kernel<false><<<gemmGrid, 256, 0, stream>>>(x, W1, nullptr, Hb, N);
    spmm_csr_kernel<true><<<spmmGrid, 256, 0, stream>>>(rowptr, pairs, Hb,
                                                        nullptr, buf1, N);
    // BN stats + fold (from bf16 h1)
    bnstats_kernel<<<400, 256, 0, stream>>>(buf1, stats, N);
    bnfinal_kernel<<<1, 128, 0, stream>>>(stats, gmm, beta, ac, 1.0f / (float)N);
    // Layer 2: Hb = bf16(relu(bn(buf1)) @ W2) ; out = A @ Hb + b2 (fp32)
    gemm_kernel<true><<<gemmGrid, 256, 0, stream>>>(buf1, W2, ac, Hb, N);
    spmm_csr_kernel<false><<<spmmGrid, 256, 0, stream>>>(rowptr, pairs, Hb,
                                                         b2, out, N);
}